// Round 3
// baseline (980.374 us; speedup 1.0000x reference)
//
#include <hip/hip_runtime.h>
#include <math.h>

#define N_NODES 50000
#define N_EDGES 400000
#define IN_F 256
#define OUT_F 64
#define ED_F 64
#define NH 4

// manual bf16 (round-to-nearest-even) to avoid header API variance
__device__ __forceinline__ unsigned short f2bf(float f) {
    unsigned u = __float_as_uint(f);
    u = (u + 0x7FFFu + ((u >> 16) & 1u)) >> 16;
    return (unsigned short)u;
}
__device__ __forceinline__ float bf2f(unsigned short b) {
    return __uint_as_float(((unsigned)b) << 16);
}

// float atomic max via monotone int/uint encoding (init pattern 0xFFFFFFFF works as -inf)
__device__ __forceinline__ void atomicMaxF(float* addr, float val) {
    if (val >= 0.f) {
        atomicMax((int*)addr, __float_as_int(val));
    } else {
        atomicMin((unsigned int*)addr, __float_as_uint(val));
    }
}

// u[h][f] = sum_g W_eatt[h][f][g] * We[h][g];  c[h] = b_eatt[h].We[h] + b_att[h]
__global__ __launch_bounds__(256) void prep_kernel(
    const float* __restrict__ W_att, const float* __restrict__ b_att,
    const float* __restrict__ W_eatt, const float* __restrict__ b_eatt,
    float* __restrict__ u, float* __restrict__ c)
{
    int t = threadIdx.x;           // 256 threads: one (h,f) each
    int h = t >> 6, f = t & 63;
    const float* We = W_att + h * (2 * OUT_F + ED_F) + 2 * OUT_F;
    float s = 0.f;
    for (int g = 0; g < ED_F; g++) s += W_eatt[(h * ED_F + f) * ED_F + g] * We[g];
    u[t] = s;
    if (f == 0) {
        float cc = b_att[h];
        for (int g = 0; g < ED_F; g++) cc += b_eatt[h * ED_F + g] * We[g];
        c[h] = cc;
    }
}

// z[h][n][o] = x[n,:] @ W_fc[h][:,o] + b_fc[h][o];  a_i/a_j = z . Wi/Wj
// block: 256 threads -> 64 nodes x 64 outs, thread = 4 nodes x 4 outs
// z stored as bf16 (workspace footprint), a_i/a_j from fp32 accumulators.
__global__ __launch_bounds__(256) void z_kernel(
    const float* __restrict__ x, const float* __restrict__ W_fc,
    const float* __restrict__ b_fc, const float* __restrict__ W_att,
    unsigned short* __restrict__ zb, float* __restrict__ a_i, float* __restrict__ a_j)
{
    const int h = blockIdx.y;
    const int n0 = blockIdx.x * 64;
    __shared__ float xt[64 * 68];    // 64 nodes x 64 k, row stride 68 (pad kills 4-way bank conflict)
    __shared__ float wt[64][64];     // k x o
    const int t = threadIdx.x;
    const int og = t & 15;           // output group -> cols o4..o4+3
    const int o4 = og << 2;
    const int ng = t >> 4;           // node group -> nodes ng*4..ng*4+3

    float acc[4][4];
#pragma unroll
    for (int i = 0; i < 4; i++)
#pragma unroll
        for (int j = 0; j < 4; j++) acc[i][j] = 0.f;

    for (int k0 = 0; k0 < IN_F; k0 += 64) {
        const float4* Wg = (const float4*)(W_fc + ((size_t)h * IN_F + k0) * OUT_F);
        float4* wt4 = (float4*)wt;
#pragma unroll
        for (int j = 0; j < 4; j++) wt4[t + j * 256] = Wg[t + j * 256];
#pragma unroll
        for (int j = 0; j < 4; j++) {
            int f4 = t + j * 256;          // 0..1023
            int nl = f4 >> 4;              // 0..63
            int kk4 = (f4 & 15) << 2;      // 0..60
            int n = n0 + nl;
            float4 v = make_float4(0.f, 0.f, 0.f, 0.f);
            if (n < N_NODES) v = *(const float4*)(x + (size_t)n * IN_F + k0 + kk4);
            *(float4*)(xt + nl * 68 + kk4) = v;
        }
        __syncthreads();
#pragma unroll
        for (int kk = 0; kk < 64; kk++) {
            const float4 w = *(const float4*)&wt[kk][o4];
            const float xv0 = xt[(ng * 4 + 0) * 68 + kk];
            const float xv1 = xt[(ng * 4 + 1) * 68 + kk];
            const float xv2 = xt[(ng * 4 + 2) * 68 + kk];
            const float xv3 = xt[(ng * 4 + 3) * 68 + kk];
            acc[0][0] += xv0 * w.x; acc[0][1] += xv0 * w.y; acc[0][2] += xv0 * w.z; acc[0][3] += xv0 * w.w;
            acc[1][0] += xv1 * w.x; acc[1][1] += xv1 * w.y; acc[1][2] += xv1 * w.z; acc[1][3] += xv1 * w.w;
            acc[2][0] += xv2 * w.x; acc[2][1] += xv2 * w.y; acc[2][2] += xv2 * w.z; acc[2][3] += xv2 * w.w;
            acc[3][0] += xv3 * w.x; acc[3][1] += xv3 * w.y; acc[3][2] += xv3 * w.z; acc[3][3] += xv3 * w.w;
        }
        __syncthreads();
    }

    const float4 bf  = *(const float4*)(b_fc + h * OUT_F + o4);
    const float4 wiv = *(const float4*)(W_att + h * 192 + o4);
    const float4 wjv = *(const float4*)(W_att + h * 192 + 64 + o4);
#pragma unroll
    for (int i = 0; i < 4; i++) {
        int n = n0 + ng * 4 + i;
        float4 v;
        v.x = acc[i][0] + bf.x; v.y = acc[i][1] + bf.y;
        v.z = acc[i][2] + bf.z; v.w = acc[i][3] + bf.w;
        float pi = v.x * wiv.x + v.y * wiv.y + v.z * wiv.z + v.w * wiv.w;
        float pj = v.x * wjv.x + v.y * wjv.y + v.z * wjv.z + v.w * wjv.w;
#pragma unroll
        for (int m = 8; m; m >>= 1) {
            pi += __shfl_xor(pi, m, 64);
            pj += __shfl_xor(pj, m, 64);
        }
        if (n < N_NODES) {
            ushort4 zv;
            zv.x = f2bf(v.x); zv.y = f2bf(v.y); zv.z = f2bf(v.z); zv.w = f2bf(v.w);
            *(ushort4*)(zb + ((size_t)h * N_NODES + n) * OUT_F + o4) = zv;
            if (og == 0) { a_i[h * N_NODES + n] = pi; a_j[h * N_NODES + n] = pj; }
        }
    }
}

// per edge: e = leaky_relu(a_i[dst] + a_j[src] + edge_attr.u[h] + c[h]); seg_max atomic
__global__ __launch_bounds__(256) void logits_kernel(
    const int* __restrict__ edge_index, const float* __restrict__ edge_attr,
    const float* __restrict__ u, const float* __restrict__ c,
    const float* __restrict__ a_i, const float* __restrict__ a_j,
    float* __restrict__ ebuf, float* __restrict__ seg_max)
{
    const int t = threadIdx.x;
    const int lane = t & 63;
    const int w = t >> 6;
    const int e = blockIdx.x * 4 + w;
    const int src = edge_index[e];
    const int dst = edge_index[N_EDGES + e];
    const float ea = edge_attr[(size_t)e * ED_F + lane];
#pragma unroll
    for (int h = 0; h < NH; h++) {
        float p = ea * u[h * 64 + lane];
#pragma unroll
        for (int m = 32; m; m >>= 1) p += __shfl_xor(p, m, 64);
        if (lane == 0) {
            float a = p + a_i[h * N_NODES + dst] + a_j[h * N_NODES + src] + c[h];
            float ev = a > 0.f ? a : 0.2f * a;
            ebuf[(size_t)h * N_EDGES + e] = ev;
            atomicMaxF(&seg_max[h * N_NODES + dst], ev);
        }
    }
}

__global__ __launch_bounds__(256) void expsum_kernel(
    const int* __restrict__ edge_index, float* __restrict__ ebuf,
    const float* __restrict__ seg_max, float* __restrict__ seg_sum)
{
    const int e = blockIdx.x * 256 + threadIdx.x;
    const int h = blockIdx.y;
    if (e >= N_EDGES) return;
    const int dst = edge_index[N_EDGES + e];
    float v = expf(ebuf[(size_t)h * N_EDGES + e] - seg_max[h * N_NODES + dst]);
    ebuf[(size_t)h * N_EDGES + e] = v;
    atomicAdd(&seg_sum[h * N_NODES + dst], v);
}

// per edge: alpha = exp/sum; msg = alpha*(z[src] + edge_attr@W_edge + b_edge); atomic scatter to out
// thread t owns column c = h*64+o; W_edge column kept in 64 VGPRs.
#define EPB 64
__global__ __launch_bounds__(256) void aggregate_kernel(
    const int* __restrict__ edge_index, const float* __restrict__ edge_attr,
    const float* __restrict__ W_edge, const float* __restrict__ b_edge,
    const unsigned short* __restrict__ zb, const float* __restrict__ seg_sum,
    float* __restrict__ ebuf, float* __restrict__ out)
{
    const int t = threadIdx.x;
    const int h = t >> 6, o = t & 63;
    float Wcol[64];
#pragma unroll
    for (int f = 0; f < 64; f++) Wcol[f] = W_edge[(size_t)(h * 64 + f) * 64 + o];
    const float bcol = b_edge[h * 64 + o];

    const int e0 = blockIdx.x * EPB;
    for (int e = e0; e < e0 + EPB; e++) {
        const int src = edge_index[e];
        const int dst = edge_index[N_EDGES + e];
        const float4* row4 = (const float4*)(edge_attr + (size_t)e * 64);
        float acc0 = bcol, acc1 = 0.f;
#pragma unroll
        for (int f = 0; f < 8; f++) {
            float4 r0 = row4[2 * f];
            float4 r1 = row4[2 * f + 1];
            acc0 += r0.x * Wcol[8 * f + 0] + r0.y * Wcol[8 * f + 1] + r0.z * Wcol[8 * f + 2] + r0.w * Wcol[8 * f + 3];
            acc1 += r1.x * Wcol[8 * f + 4] + r1.y * Wcol[8 * f + 5] + r1.z * Wcol[8 * f + 6] + r1.w * Wcol[8 * f + 7];
        }
        const float ez = acc0 + acc1;
        const float zv = bf2f(zb[((size_t)h * N_NODES + src) * 64 + o]);
        const float ex = ebuf[(size_t)h * N_EDGES + e];
        const float al = ex / seg_sum[h * N_NODES + dst];
        if (o == 0) ebuf[(size_t)h * N_EDGES + e] = al;
        atomicAdd(&out[(size_t)dst * (NH * OUT_F) + h * 64 + o], al * (zv + ez));
    }
}

extern "C" void kernel_launch(void* const* d_in, const int* in_sizes, int n_in,
                              void* d_out, int out_size, void* d_ws, size_t ws_size,
                              hipStream_t stream) {
    const float* x         = (const float*)d_in[0];
    const int*   edge_index= (const int*)  d_in[1];
    const float* edge_attr = (const float*)d_in[2];
    const float* W_fc      = (const float*)d_in[3];
    const float* b_fc      = (const float*)d_in[4];
    const float* W_att     = (const float*)d_in[5];
    const float* b_att     = (const float*)d_in[6];
    const float* W_edge    = (const float*)d_in[7];
    const float* b_edge    = (const float*)d_in[8];
    const float* W_eatt    = (const float*)d_in[9];
    const float* b_eatt    = (const float*)d_in[10];

    float* out  = (float*)d_out;                          // (N, H*OUT)
    float* ebuf = out + (size_t)N_NODES * NH * OUT_F;     // (H, E) alpha slot, reused for e/exp

    // workspace layout (bytes): zb bf16 H*N*64 (25.6MB) | a_i,a_j,seg_max,seg_sum fp32 (3.2MB) | u,c
    unsigned short* zb = (unsigned short*)d_ws;
    float* fws     = (float*)(zb + (size_t)NH * N_NODES * OUT_F);
    float* a_i     = fws;
    float* a_j     = a_i + NH * N_NODES;
    float* seg_max = a_j + NH * N_NODES;
    float* seg_sum = seg_max + NH * N_NODES;
    float* u       = seg_sum + NH * N_NODES;              // H*64
    float* c       = u + NH * 64;                         // H

    size_t need = (size_t)NH * N_NODES * OUT_F * 2          // zb
                + (size_t)(4 * NH * N_NODES + NH * 64 + NH) * 4;

    // always zero the output (harness poisons it with 0xAA)
    hipMemsetAsync(out, 0, (size_t)N_NODES * NH * OUT_F * sizeof(float), stream);

    if (ws_size < need) {
        // workspace too small: leave output zeroed -> deterministic finite-absmax
        // failure instead of an OOB fault that kills the container. (canary)
        hipMemsetAsync(ebuf, 0, (size_t)NH * N_EDGES * sizeof(float), stream);
        return;
    }

    hipMemsetAsync(seg_sum, 0, (size_t)NH * N_NODES * sizeof(float), stream);
    hipMemsetAsync(seg_max, 0xFF, (size_t)NH * N_NODES * sizeof(float), stream); // acts as -inf for atomicMaxF

    prep_kernel<<<1, 256, 0, stream>>>(W_att, b_att, W_eatt, b_eatt, u, c);

    dim3 zg((N_NODES + 63) / 64, NH);
    z_kernel<<<zg, 256, 0, stream>>>(x, W_fc, b_fc, W_att, zb, a_i, a_j);

    logits_kernel<<<N_EDGES / 4, 256, 0, stream>>>(edge_index, edge_attr, u, c, a_i, a_j, ebuf, seg_max);

    dim3 eg((N_EDGES + 255) / 256, NH);
    expsum_kernel<<<eg, 256, 0, stream>>>(edge_index, ebuf, seg_max, seg_sum);

    aggregate_kernel<<<N_EDGES / EPB, 256, 0, stream>>>(edge_index, edge_attr, W_edge, b_edge,
                                                        zb, seg_sum, ebuf, out);
}

// Round 5
// 912.289 us; speedup vs baseline: 1.0746x; 1.0746x over previous
//
#include <hip/hip_runtime.h>
#include <math.h>

#define N_NODES 50000
#define N_EDGES 400000
#define IN_F 256
#define OUT_F 64
#define ED_F 64
#define NH 4

using f16x8 = __attribute__((ext_vector_type(8))) _Float16;
using f32x4 = __attribute__((ext_vector_type(4))) float;

// float atomic max via monotone int/uint encoding (init pattern 0xFFFFFFFF works as -inf)
__device__ __forceinline__ void atomicMaxF(float* addr, float val) {
    if (val >= 0.f) {
        atomicMax((int*)addr, __float_as_int(val));
    } else {
        atomicMin((unsigned int*)addr, __float_as_uint(val));
    }
}

// block 0: u[h][f] = sum_g W_eatt[h][f][g]*We[h][g]; c[h] = b_att[h] + b_eatt[h].We[h]
// blocks 1..32: Wfcfrag (f16, MFMA b-frag order), blocks 33..40: Wefrag
__global__ __launch_bounds__(256) void prep_kernel(
    const float* __restrict__ W_att, const float* __restrict__ b_att,
    const float* __restrict__ W_eatt, const float* __restrict__ b_eatt,
    const float* __restrict__ W_fc, const float* __restrict__ W_edge,
    float* __restrict__ u, float* __restrict__ c,
    _Float16* __restrict__ Wfcfrag, _Float16* __restrict__ Wefrag)
{
    const int b = blockIdx.x, t = threadIdx.x;
    if (b == 0) {
        int h = t >> 6, f = t & 63;
        const float* We = W_att + h * (2 * OUT_F + ED_F) + 2 * OUT_F;
        float s = 0.f;
        for (int g = 0; g < ED_F; g++) s += W_eatt[(h * ED_F + f) * ED_F + g] * We[g];
        u[t] = s;
        if (f == 0) {
            float cc = b_att[h];
            for (int g = 0; g < ED_F; g++) cc += b_eatt[h * ED_F + g] * We[g];
            c[h] = cc;
        }
    } else if (b <= 32) {
        // b_frag[lane][j] = B[k=quad*8+j][n=lane&15], B = W_fc[h] (256x64)
        int idx = b - 1;
        int h = idx >> 3, kt = idx & 7;
        int lane = t & 63, nt = t >> 6;
        int q = lane >> 4, l15 = lane & 15;
        f16x8 w;
#pragma unroll
        for (int j = 0; j < 8; j++) {
            int k = kt * 32 + q * 8 + j;
            int o = nt * 16 + l15;
            w[j] = (_Float16)W_fc[((size_t)h * IN_F + k) * OUT_F + o];
        }
        *(f16x8*)&Wfcfrag[(size_t)(((h * 8 + kt) * 4 + nt) * 64 + lane) * 8] = w;
    } else {
        int idx = b - 33;
        int h = idx >> 1, kt = idx & 1;
        int lane = t & 63, nt = t >> 6;
        int q = lane >> 4, l15 = lane & 15;
        f16x8 w;
#pragma unroll
        for (int j = 0; j < 8; j++) {
            int k = kt * 32 + q * 8 + j;
            int o = nt * 16 + l15;
            w[j] = (_Float16)W_edge[((size_t)h * ED_F + k) * OUT_F + o];
        }
        *(f16x8*)&Wefrag[(size_t)(((h * 2 + kt) * 4 + nt) * 64 + lane) * 8] = w;
    }
}

// z[h][n][o] = x@W_fc + b_fc, f16 MFMA 16x16x32. Block: 64 nodes, 4 waves = 4 heads.
__global__ __launch_bounds__(256) void z_gemm(
    const float* __restrict__ x, const _Float16* __restrict__ Wfcfrag,
    const float* __restrict__ b_fc, _Float16* __restrict__ zb)
{
    __shared__ _Float16 aLDS[32 * 64 * 8];   // 32 chunks(kt,quad) x 64 nodes x 8 f16 = 32KB
    const int t = threadIdx.x;
    const int n0 = blockIdx.x * 64;
    const int lane = t & 63, h = t >> 6;
    const int q = lane >> 4, l15 = lane & 15;

    // stage x tile (64 nodes x 256 k) fp32 -> f16 frag-order LDS
    {
        const int m = t >> 2, qq = t & 3;
        const int n = n0 + m;
#pragma unroll
        for (int p = 0; p < 4; p++) {
            float4 v4[4];
            if (n < N_NODES) {
                const float4* xp = (const float4*)(x + (size_t)n * IN_F + p * 64 + qq * 16);
#pragma unroll
                for (int k = 0; k < 4; k++) v4[k] = xp[k];
            } else {
#pragma unroll
                for (int k = 0; k < 4; k++) v4[k] = make_float4(0.f, 0.f, 0.f, 0.f);
            }
            const float* vv = (const float*)v4;
#pragma unroll
            for (int i = 0; i < 2; i++) {
                int c8 = p * 8 + qq * 2 + i;
                f16x8 w;
#pragma unroll
                for (int j = 0; j < 8; j++) w[j] = (_Float16)vv[i * 8 + j];
                *(f16x8*)&aLDS[(c8 * 64 + m) * 8] = w;
            }
        }
    }
    __syncthreads();

    f32x4 acc[4][4];
#pragma unroll
    for (int mt = 0; mt < 4; mt++)
#pragma unroll
        for (int nt = 0; nt < 4; nt++) acc[mt][nt] = (f32x4)0.f;

    for (int kt = 0; kt < 8; kt++) {
        f16x8 bfr[4];
#pragma unroll
        for (int nt = 0; nt < 4; nt++)
            bfr[nt] = *(const f16x8*)&Wfcfrag[(size_t)(((h * 8 + kt) * 4 + nt) * 64 + lane) * 8];
        f16x8 afr[4];
#pragma unroll
        for (int mt = 0; mt < 4; mt++)
            afr[mt] = *(f16x8*)&aLDS[((kt * 4 + q) * 64 + mt * 16 + l15) * 8];
#pragma unroll
        for (int mt = 0; mt < 4; mt++)
#pragma unroll
            for (int nt = 0; nt < 4; nt++)
                acc[mt][nt] = __builtin_amdgcn_mfma_f32_16x16x32_f16(afr[mt], bfr[nt], acc[mt][nt], 0, 0, 0);
    }

    float bfc[4];
#pragma unroll
    for (int nt = 0; nt < 4; nt++) bfc[nt] = b_fc[h * OUT_F + nt * 16 + l15];

    // C/D layout: col = lane&15, row = quad*4 + reg
#pragma unroll
    for (int mt = 0; mt < 4; mt++) {
#pragma unroll
        for (int r = 0; r < 4; r++) {
            int node = n0 + mt * 16 + q * 4 + r;
            if (node < N_NODES) {
                _Float16* zrow = zb + ((size_t)h * N_NODES + node) * OUT_F;
#pragma unroll
                for (int nt = 0; nt < 4; nt++)
                    zrow[nt * 16 + l15] = (_Float16)(acc[mt][nt][r] + bfc[nt]);
            }
        }
    }
}

// a_i/a_j = z . Wi / Wj (fp32 weights, f16 z). wave = head, 16 nodes/block.
__global__ __launch_bounds__(256) void a_ij_kernel(
    const _Float16* __restrict__ zb, const float* __restrict__ W_att,
    float* __restrict__ a_i, float* __restrict__ a_j)
{
    const int t = threadIdx.x, h = t >> 6, lane = t & 63;
    const float wi = W_att[h * 192 + lane];
    const float wj = W_att[h * 192 + 64 + lane];
    const int nb = blockIdx.x * 16;
    for (int i = 0; i < 16; i++) {
        int n = nb + i;
        float zv = (float)zb[((size_t)h * N_NODES + n) * OUT_F + lane];
        float pi = zv * wi, pj = zv * wj;
#pragma unroll
        for (int m = 32; m; m >>= 1) {
            pi += __shfl_xor(pi, m, 64);
            pj += __shfl_xor(pj, m, 64);
        }
        if (lane == 0) { a_i[h * N_NODES + n] = pi; a_j[h * N_NODES + n] = pj; }
    }
}

// per edge: e = leaky_relu(a_i[dst] + a_j[src] + edge_attr.u[h] + c[h]); seg_max atomic
__global__ __launch_bounds__(256) void logits_kernel(
    const int* __restrict__ edge_index, const float* __restrict__ edge_attr,
    const float* __restrict__ u, const float* __restrict__ c,
    const float* __restrict__ a_i, const float* __restrict__ a_j,
    float* __restrict__ ebuf, float* __restrict__ seg_max)
{
    const int t = threadIdx.x;
    const int lane = t & 63;
    const int w = t >> 6;
    const int e = blockIdx.x * 4 + w;
    const int src = edge_index[e];
    const int dst = edge_index[N_EDGES + e];
    const float ea = edge_attr[(size_t)e * ED_F + lane];
#pragma unroll
    for (int h = 0; h < NH; h++) {
        float p = ea * u[h * 64 + lane];
#pragma unroll
        for (int m = 32; m; m >>= 1) p += __shfl_xor(p, m, 64);
        if (lane == 0) {
            float a = p + a_i[h * N_NODES + dst] + a_j[h * N_NODES + src] + c[h];
            float ev = a > 0.f ? a : 0.2f * a;
            ebuf[(size_t)h * N_EDGES + e] = ev;
            atomicMaxF(&seg_max[h * N_NODES + dst], ev);
        }
    }
}

__global__ __launch_bounds__(256) void expsum_kernel(
    const int* __restrict__ edge_index, float* __restrict__ ebuf,
    const float* __restrict__ seg_max, float* __restrict__ seg_sum)
{
    const int e = blockIdx.x * 256 + threadIdx.x;
    const int h = blockIdx.y;
    if (e >= N_EDGES) return;
    const int dst = edge_index[N_EDGES + e];
    float v = expf(ebuf[(size_t)h * N_EDGES + e] - seg_max[h * N_NODES + dst]);
    ebuf[(size_t)h * N_EDGES + e] = v;
    atomicAdd(&seg_sum[h * N_NODES + dst], v);
}

// fused: ez = edge_attr@W_edge (f16 MFMA) + b_edge; msg = alpha*(z[src]+ez); atomic scatter.
// Block: 64 edges, 4 waves = 4 heads. Also writes alpha to ebuf (output 1).
__global__ __launch_bounds__(256) void aggregate_mfma(
    const int* __restrict__ edge_index, const float* __restrict__ edge_attr,
    const _Float16* __restrict__ Wefrag, const float* __restrict__ b_edge,
    const _Float16* __restrict__ zb, const float* __restrict__ seg_sum,
    float* __restrict__ ebuf, float* __restrict__ out)
{
    __shared__ _Float16 aLDS[8 * 64 * 8];   // 8 chunks x 64 edges x 8 f16 = 8KB
    __shared__ int srcS[64], dstS[64];
    __shared__ float alphaS[NH][64];
    const int t = threadIdx.x;
    const int e0 = blockIdx.x * 64;
    const int lane = t & 63, h = t >> 6;
    const int q = lane >> 4, l15 = lane & 15;

    if (t < 64) srcS[t] = edge_index[e0 + t];
    else if (t < 128) dstS[t - 64] = edge_index[N_EDGES + e0 + t - 64];

    // stage edge_attr tile (64 edges x 64 f) fp32 -> f16 frag-order LDS
    {
        const int m = t >> 2, qq = t & 3;
        const float4* ap = (const float4*)(edge_attr + (size_t)(e0 + m) * ED_F + qq * 16);
        float4 v4[4];
#pragma unroll
        for (int k = 0; k < 4; k++) v4[k] = ap[k];
        const float* vv = (const float*)v4;
#pragma unroll
        for (int i = 0; i < 2; i++) {
            int c8 = qq * 2 + i;
            f16x8 w;
#pragma unroll
            for (int j = 0; j < 8; j++) w[j] = (_Float16)vv[i * 8 + j];
            *(f16x8*)&aLDS[(c8 * 64 + m) * 8] = w;
        }
    }
    __syncthreads();

    // alpha for own wave's head (writer wave == reader wave for alphaS[h][*])
    {
        int el = lane;
        float ex = ebuf[(size_t)h * N_EDGES + e0 + el];
        float al = ex / seg_sum[h * N_NODES + dstS[el]];
        alphaS[h][el] = al;
        ebuf[(size_t)h * N_EDGES + e0 + el] = al;   // alpha output
    }

    f16x8 wf[2][4];
#pragma unroll
    for (int kt = 0; kt < 2; kt++)
#pragma unroll
        for (int nt = 0; nt < 4; nt++)
            wf[kt][nt] = *(const f16x8*)&Wefrag[(size_t)(((h * 2 + kt) * 4 + nt) * 64 + lane) * 8];
    float be[4];
#pragma unroll
    for (int nt = 0; nt < 4; nt++) be[nt] = b_edge[h * OUT_F + nt * 16 + l15];

    f32x4 acc[4][4];
#pragma unroll
    for (int mt = 0; mt < 4; mt++)
#pragma unroll
        for (int nt = 0; nt < 4; nt++) acc[mt][nt] = (f32x4)0.f;

#pragma unroll
    for (int kt = 0; kt < 2; kt++) {
        f16x8 afr[4];
#pragma unroll
        for (int mt = 0; mt < 4; mt++)
            afr[mt] = *(f16x8*)&aLDS[((kt * 4 + q) * 64 + mt * 16 + l15) * 8];
#pragma unroll
        for (int mt = 0; mt < 4; mt++)
#pragma unroll
            for (int nt = 0; nt < 4; nt++)
                acc[mt][nt] = __builtin_amdgcn_mfma_f32_16x16x32_f16(afr[mt], wf[kt][nt], acc[mt][nt], 0, 0, 0);
    }

    // epilogue: C row = edge (quad*4+reg), col = o (lane&15 within nt tile)
#pragma unroll
    for (int mt = 0; mt < 4; mt++) {
#pragma unroll
        for (int r = 0; r < 4; r++) {
            int el = mt * 16 + q * 4 + r;
            float al = alphaS[h][el];
            int s = srcS[el], d = dstS[el];
            const _Float16* zrow = zb + ((size_t)h * N_NODES + s) * OUT_F;
            float* orow = out + (size_t)d * (NH * OUT_F) + h * OUT_F;
#pragma unroll
            for (int nt = 0; nt < 4; nt++) {
                float zv = (float)zrow[nt * 16 + l15];
                atomicAdd(&orow[nt * 16 + l15], al * (acc[mt][nt][r] + be[nt] + zv));
            }
        }
    }
}

extern "C" void kernel_launch(void* const* d_in, const int* in_sizes, int n_in,
                              void* d_out, int out_size, void* d_ws, size_t ws_size,
                              hipStream_t stream) {
    const float* x         = (const float*)d_in[0];
    const int*   edge_index= (const int*)  d_in[1];
    const float* edge_attr = (const float*)d_in[2];
    const float* W_fc      = (const float*)d_in[3];
    const float* b_fc      = (const float*)d_in[4];
    const float* W_att     = (const float*)d_in[5];
    const float* b_att     = (const float*)d_in[6];
    const float* W_edge    = (const float*)d_in[7];
    const float* b_edge    = (const float*)d_in[8];
    const float* W_eatt    = (const float*)d_in[9];
    const float* b_eatt    = (const float*)d_in[10];

    float* out  = (float*)d_out;                          // (N, H*OUT)
    float* ebuf = out + (size_t)N_NODES * NH * OUT_F;     // (H, E): logits -> exp -> alpha

    // ws: zb f16 (25.6MB) | a_i,a_j,seg_max,seg_sum fp32 (3.2MB) | u,c | Wfcfrag (128KB) | Wefrag (32KB)
    _Float16* zb   = (_Float16*)d_ws;
    float* fws     = (float*)(zb + (size_t)NH * N_NODES * OUT_F);
    float* a_i     = fws;
    float* a_j     = a_i + NH * N_NODES;
    float* seg_max = a_j + NH * N_NODES;
    float* seg_sum = seg_max + NH * N_NODES;
    float* u       = seg_sum + NH * N_NODES;              // H*64
    float* c       = u + NH * 64;                         // H
    _Float16* Wfcfrag = (_Float16*)(c + NH);              // H*8*4*64*8 = 65536 halves
    _Float16* Wefrag  = Wfcfrag + NH * 8 * 4 * 64 * 8;    // H*2*4*64*8 = 16384 halves

    size_t need = (size_t)NH * N_NODES * OUT_F * 2
                + (size_t)(4 * NH * N_NODES + NH * 64 + NH) * 4
                + (size_t)(NH * 8 * 4 * 64 * 8 + NH * 2 * 4 * 64 * 8) * 2;

    hipMemsetAsync(out, 0, (size_t)N_NODES * NH * OUT_F * sizeof(float), stream);

    if (ws_size < need) {
        // graceful finite-absmax failure instead of OOB fault (canary)
        hipMemsetAsync(ebuf, 0, (size_t)NH * N_EDGES * sizeof(float), stream);
        return;
    }

    hipMemsetAsync(seg_sum, 0, (size_t)NH * N_NODES * sizeof(float), stream);
    hipMemsetAsync(seg_max, 0xFF, (size_t)NH * N_NODES * sizeof(float), stream); // -inf for atomicMaxF

    prep_kernel<<<41, 256, 0, stream>>>(W_att, b_att, W_eatt, b_eatt, W_fc, W_edge,
                                        u, c, Wfcfrag, Wefrag);

    z_gemm<<<(N_NODES + 63) / 64, 256, 0, stream>>>(x, Wfcfrag, b_fc, zb);

    a_ij_kernel<<<N_NODES / 16, 256, 0, stream>>>(zb, W_att, a_i, a_j);

    logits_kernel<<<N_EDGES / 4, 256, 0, stream>>>(edge_index, edge_attr, u, c, a_i, a_j, ebuf, seg_max);

    dim3 eg((N_EDGES + 255) / 256, NH);
    expsum_kernel<<<eg, 256, 0, stream>>>(edge_index, ebuf, seg_max, seg_sum);

    aggregate_mfma<<<N_EDGES / 64, 256, 0, stream>>>(edge_index, edge_attr, Wefrag, b_edge,
                                                     zb, seg_sum, ebuf, out);
}